// Round 9
// baseline (126.787 us; speedup 1.0000x reference)
//
#include <hip/hip_runtime.h>
#include <math.h>

#define BB 8
#define TT 2048
#define DD 32
#define HH 4
#define HD 8
#define NROWS (BB*TT)       // 16384 (B*T); attention rows = B*H*T = 65536
#define LNEPS 1e-5f

#if __has_builtin(__builtin_amdgcn_exp2f)
#define EXP2F(x) __builtin_amdgcn_exp2f(x)
#else
#define EXP2F(x) __expf(0.6931471805599453f*(x))
#endif

typedef _Float16 h2 __attribute__((ext_vector_type(2)));
typedef _Float16 h4v __attribute__((ext_vector_type(4)));
typedef _Float16 h8v __attribute__((ext_vector_type(8)));
typedef float f32x16 __attribute__((ext_vector_type(16)));
struct KH { h2 a, b, c, d; };               // 16B: 8 halves
union F4H { float4 f; KH k; };

static __device__ __forceinline__ h2 pkrtz(float a, float b) {
    return __builtin_bit_cast(h2, __builtin_amdgcn_cvt_pkrtz(a, b));
}
static __device__ __forceinline__ unsigned pkrtz_u(float a, float b) {
    return __builtin_bit_cast(unsigned, __builtin_amdgcn_cvt_pkrtz(a, b));
}
static __device__ __forceinline__ unsigned short f16u(float x) {
    return __builtin_bit_cast(unsigned short, (_Float16)x);
}

#if __has_builtin(__builtin_amdgcn_fdot2)
#define DOT2(a,b,c) __builtin_amdgcn_fdot2((a),(b),(c),false)
#else
#define DOT2(a,b,c) fmaf((float)(a)[1],(float)(b)[1], fmaf((float)(a)[0],(float)(b)[0],(c)))
#endif

// ---------------- Kernel 1: LN1 + QKV projection (8 threads/row) ----------------
__global__ __launch_bounds__(256) void k_ln_qkv(
    const float* __restrict__ x,
    const float* __restrict__ Wq, const float* __restrict__ Wk, const float* __restrict__ Wv,
    const float* __restrict__ g, const float* __restrict__ b,
    float* __restrict__ h, float* __restrict__ qh,
    float* __restrict__ Kh, float* __restrict__ Vt)
{
    __shared__ float sW[3*HH*264];
    __shared__ float sg[DD], sb[DD];
    for (int i = threadIdx.x; i < HH*DD*HD; i += 256) {
        int hd_ = i >> 8, off = i & 255;
        sW[hd_*264 + off]              = Wq[i];
        sW[(4+hd_)*264 + off]          = Wk[i];
        sW[(8+hd_)*264 + off]          = Wv[i];
    }
    if (threadIdx.x < DD) { sg[threadIdx.x] = g[threadIdx.x]; sb[threadIdx.x] = b[threadIdx.x]; }
    __syncthreads();

    int idx = blockIdx.x * 256 + threadIdx.x;     // 0..131071
    int r   = idx >> 3;                           // row 0..16383
    int sub = idx & 7;
    int hh  = sub & 3;
    int dh  = sub >> 2;                           // 0/1 -> dims dh*16..+15
    int bb  = r >> 11, tt = r & 2047;

    float xr[16];
    {
        const float4* xp = (const float4*)(x + (size_t)r * DD + dh*16);
        float4 t0 = xp[0], t1 = xp[1], t2 = xp[2], t3 = xp[3];
        xr[0]=t0.x; xr[1]=t0.y; xr[2]=t0.z; xr[3]=t0.w;
        xr[4]=t1.x; xr[5]=t1.y; xr[6]=t1.z; xr[7]=t1.w;
        xr[8]=t2.x; xr[9]=t2.y; xr[10]=t2.z; xr[11]=t2.w;
        xr[12]=t3.x; xr[13]=t3.y; xr[14]=t3.z; xr[15]=t3.w;
    }
    float s1 = 0.f;
    #pragma unroll
    for (int i = 0; i < 16; ++i) s1 += xr[i];
    s1 += __shfl_xor(s1, 4, 64);
    float mu = s1 * (1.f/DD);
    float sq = 0.f;
    #pragma unroll
    for (int i = 0; i < 16; ++i) { float d = xr[i]-mu; sq += d*d; }
    sq += __shfl_xor(sq, 4, 64);
    float rs = rsqrtf(sq * (1.f/DD) + LNEPS);

    float hr[16];
    #pragma unroll
    for (int i = 0; i < 16; ++i) hr[i] = (xr[i]-mu)*rs*sg[dh*16+i] + sb[dh*16+i];

    {
        float4* hp = (float4*)(h + (size_t)r * DD + dh*16);
        hp[0]=make_float4(hr[0],hr[1],hr[2],hr[3]);
        hp[1]=make_float4(hr[4],hr[5],hr[6],hr[7]);
        hp[2]=make_float4(hr[8],hr[9],hr[10],hr[11]);
        hp[3]=make_float4(hr[12],hr[13],hr[14],hr[15]);
    }

    const float* wq = sW + hh*264 + dh*128;
    const float* wk = sW + (4+hh)*264 + dh*128;
    const float* wv = sW + (8+hh)*264 + dh*128;
    float qa[HD], ka[HD], va[HD];
    #pragma unroll
    for (int k2 = 0; k2 < HD; ++k2) { qa[k2]=0.f; ka[k2]=0.f; va[k2]=0.f; }
    #pragma unroll
    for (int d = 0; d < 16; ++d) {
        float hv = hr[d];
        const float4* wq4 = (const float4*)(wq + d*8);
        const float4* wk4 = (const float4*)(wk + d*8);
        const float4* wv4 = (const float4*)(wv + d*8);
        float4 a0 = wq4[0], a1 = wq4[1];
        float4 b0 = wk4[0], b1 = wk4[1];
        float4 c0 = wv4[0], c1 = wv4[1];
        qa[0]=fmaf(hv,a0.x,qa[0]); qa[1]=fmaf(hv,a0.y,qa[1]); qa[2]=fmaf(hv,a0.z,qa[2]); qa[3]=fmaf(hv,a0.w,qa[3]);
        qa[4]=fmaf(hv,a1.x,qa[4]); qa[5]=fmaf(hv,a1.y,qa[5]); qa[6]=fmaf(hv,a1.z,qa[6]); qa[7]=fmaf(hv,a1.w,qa[7]);
        ka[0]=fmaf(hv,b0.x,ka[0]); ka[1]=fmaf(hv,b0.y,ka[1]); ka[2]=fmaf(hv,b0.z,ka[2]); ka[3]=fmaf(hv,b0.w,ka[3]);
        ka[4]=fmaf(hv,b1.x,ka[4]); ka[5]=fmaf(hv,b1.y,ka[5]); ka[6]=fmaf(hv,b1.z,ka[6]); ka[7]=fmaf(hv,b1.w,ka[7]);
        va[0]=fmaf(hv,c0.x,va[0]); va[1]=fmaf(hv,c0.y,va[1]); va[2]=fmaf(hv,c0.z,va[2]); va[3]=fmaf(hv,c0.w,va[3]);
        va[4]=fmaf(hv,c1.x,va[4]); va[5]=fmaf(hv,c1.y,va[5]); va[6]=fmaf(hv,c1.z,va[6]); va[7]=fmaf(hv,c1.w,va[7]);
    }
    #pragma unroll
    for (int k2 = 0; k2 < HD; ++k2) {
        qa[k2] += __shfl_xor(qa[k2], 4, 64);
        ka[k2] += __shfl_xor(ka[k2], 4, 64);
        va[k2] += __shfl_xor(va[k2], 4, 64);
    }

    const float SCL = 0.35355339059327373f * 1.4426950408889634f;  // 1/sqrt(8)*log2e
    size_t key = (size_t)(bb*HH + hh)*TT + tt;
    unsigned short* vtb = (unsigned short*)Vt + (size_t)(bb*HH + hh)*8*TT + tt;
    if (dh == 0) {
        F4H u;
        u.k.a = pkrtz(qa[0]*SCL, qa[1]*SCL);
        u.k.b = pkrtz(qa[2]*SCL, qa[3]*SCL);
        u.k.c = pkrtz(qa[4]*SCL, qa[5]*SCL);
        u.k.d = pkrtz(qa[6]*SCL, qa[7]*SCL);
        *(float4*)(qh + key*4) = u.f;
        vtb[(size_t)0*TT] = f16u(va[0]);
        vtb[(size_t)1*TT] = f16u(va[1]);
        vtb[(size_t)2*TT] = f16u(va[2]);
        vtb[(size_t)3*TT] = f16u(va[3]);
    } else {
        // K fragment-major: plane0 = halves 0-3, plane1 = halves 4-7
        char* Kb8 = (char*)Kh + (size_t)(bb*HH + hh)*32768;
        uint2 k01; k01.x = pkrtz_u(ka[0],ka[1]); k01.y = pkrtz_u(ka[2],ka[3]);
        uint2 k23; k23.x = pkrtz_u(ka[4],ka[5]); k23.y = pkrtz_u(ka[6],ka[7]);
        *(uint2*)(Kb8 + (size_t)tt*8) = k01;
        *(uint2*)(Kb8 + 16384 + (size_t)tt*8) = k23;
        vtb[(size_t)4*TT] = f16u(va[4]);
        vtb[(size_t)5*TT] = f16u(va[5]);
        vtb[(size_t)6*TT] = f16u(va[6]);
        vtb[(size_t)7*TT] = f16u(va[7]);
    }
}

// ---------------- Kernel 2: 32x32 MFMA flash attention, 4-way key split ----------
// Block = 1 q-tile (32 queries), 4 waves take keys c = p (mod 4). Operands loaded
// directly from L2 (no LDS staging, no main-loop barriers), pipelined 1 chunk ahead.
template<bool DIAG>
__device__ __forceinline__ void chunk_compute(
    uint2 kraw, uint4 v0r, uint4 v1r, int hi, int col,
    h4v qf, float& m, float& l, f32x16& acc)
{
    h4v kf = __builtin_bit_cast(h4v, kraw);
    f32x16 cin;
    #pragma unroll
    for (int r2 = 0; r2 < 16; ++r2) cin[r2] = -m;
    f32x16 S = __builtin_amdgcn_mfma_f32_32x32x8f16(kf, qf, cin, 0, 0, 0);
    if (DIAG) {
        #pragma unroll
        for (int r2 = 0; r2 < 16; ++r2) {
            int row = (r2&3) + 8*(r2>>2) + 4*hi;
            if (row > col) S[r2] = -1e30f;
        }
    }
    float pm = S[0];
    #pragma unroll
    for (int r2 = 1; r2 < 16; ++r2) pm = fmaxf(pm, S[r2]);
    pm = fmaxf(pm, __shfl_xor(pm, 32, 64));
    if (__builtin_expect(__any(pm > 8.f), 0)) {       // defer-max: rare rescale
        float adj = fmaxf(pm, 0.f);
        float cr  = EXP2F(-adj);
        l *= cr;
        #pragma unroll
        for (int r2 = 0; r2 < 16; ++r2) {
            int row = (r2&3) + 8*(r2>>2) + 4*hi;
            acc[r2] *= __shfl(cr, row, 64);
        }
        #pragma unroll
        for (int r2 = 0; r2 < 16; ++r2) S[r2] -= adj;
        m += adj;
    }
    float p[16];
    #pragma unroll
    for (int r2 = 0; r2 < 16; ++r2) p[r2] = EXP2F(S[r2]);
    unsigned pa_ = pkrtz_u(p[0],  p[1]);
    unsigned pb_ = pkrtz_u(p[2],  p[3]);
    unsigned pc_ = pkrtz_u(p[4],  p[5]);
    unsigned pd_ = pkrtz_u(p[6],  p[7]);
    unsigned pe_ = pkrtz_u(p[8],  p[9]);
    unsigned pf_ = pkrtz_u(p[10], p[11]);
    unsigned pg_ = pkrtz_u(p[12], p[13]);
    unsigned ph_ = pkrtz_u(p[14], p[15]);
    const h2 one2 = {(_Float16)1.f, (_Float16)1.f};
    l = DOT2(__builtin_bit_cast(h2, pa_), one2, l);
    l = DOT2(__builtin_bit_cast(h2, pb_), one2, l);
    l = DOT2(__builtin_bit_cast(h2, pc_), one2, l);
    l = DOT2(__builtin_bit_cast(h2, pd_), one2, l);
    l = DOT2(__builtin_bit_cast(h2, pe_), one2, l);
    l = DOT2(__builtin_bit_cast(h2, pf_), one2, l);
    l = DOT2(__builtin_bit_cast(h2, pg_), one2, l);
    l = DOT2(__builtin_bit_cast(h2, ph_), one2, l);
    unsigned ra = (unsigned)__shfl_xor((int)pa_, 32, 64);
    unsigned rb = (unsigned)__shfl_xor((int)pb_, 32, 64);
    unsigned rc = (unsigned)__shfl_xor((int)pc_, 32, 64);
    unsigned rd = (unsigned)__shfl_xor((int)pd_, 32, 64);
    unsigned re = (unsigned)__shfl_xor((int)pe_, 32, 64);
    unsigned rf = (unsigned)__shfl_xor((int)pf_, 32, 64);
    unsigned rg = (unsigned)__shfl_xor((int)pg_, 32, 64);
    unsigned rh = (unsigned)__shfl_xor((int)ph_, 32, 64);
    bool H = (hi != 0);
    uint4 A0 = { H?rc:pa_, H?rd:pb_, H?pc_:ra, H?pd_:rb };   // PV keys +0..15
    uint4 A1 = { H?rg:pe_, H?rh:pf_, H?pg_:re, H?ph_:rf };   // PV keys +16..31
    acc = __builtin_amdgcn_mfma_f32_32x32x16_f16(
        __builtin_bit_cast(h8v, A0), __builtin_bit_cast(h8v, v0r), acc, 0, 0, 0);
    acc = __builtin_amdgcn_mfma_f32_32x32x16_f16(
        __builtin_bit_cast(h8v, A1), __builtin_bit_cast(h8v, v1r), acc, 0, 0, 0);
}

__global__ __launch_bounds__(256) void k_attn(
    const float* __restrict__ qh, const float* __restrict__ Kh,
    const float* __restrict__ Vt, float* __restrict__ o)
{
    __shared__ float mb[4][32];
    __shared__ float lb[4][32];
    __shared__ float ob[3][256];              // partial O of waves 1..3
    const int tid  = threadIdx.x;
    const int p    = tid >> 6;                // key phase = wave
    const int lane = tid & 63;
    const int hi   = lane >> 5;
    const int col  = lane & 31;
    const int T    = blockIdx.x;              // tile id 0..2047
    const int qi   = 63 - (T >> 5);           // q-tile index (heavy first)
    const int bh   = T & 31;
    const int wq0  = qi << 5;

    const char* Kg = (const char*)Kh + (size_t)bh * 32768;   // [plane][2048 keys][8B]
    const char* Vg = (const char*)Vt + (size_t)bh * 32768;   // V^T [8 d][2048 keys]*2B
    const char* Qg = (const char*)qh + (size_t)bh * 32768 + (size_t)wq0 * 16;
    const char* vrow = Vg + (size_t)(col & 7) * 4096;

    // Q B-frag: col = query, k = 4*hi + i
    h4v qf = __builtin_bit_cast(h4v, *(const uint2*)(Qg + col*16 + hi*8));

    f32x16 acc;
    #pragma unroll
    for (int r2 = 0; r2 < 16; ++r2) acc[r2] = 0.f;
    float m = 0.f, l = 0.f;

#define LOADC(c, K2, V0, V1) do { \
    K2 = *(const uint2*)(Kg + hi*16384 + (size_t)((((c)<<5) + col))*8); \
    V0 = *(const uint4*)(vrow + (size_t)((((c)<<5) + (hi<<3)))*2); \
    V1 = *(const uint4*)(vrow + (size_t)((((c)<<5) + 16 + (hi<<3)))*2); \
} while (0)

    if (qi >= p) {
        const int last = qi - ((qi - p) & 3);     // largest c <= qi with c = p (mod 4)
        uint2 kc_; uint4 v0c, v1c;
        LOADC(p, kc_, v0c, v1c);
        int c = p;
        while (c < last) {
            uint2 kn_; uint4 v0n, v1n;
            LOADC(c + 4, kn_, v0n, v1n);
            chunk_compute<false>(kc_, v0c, v1c, hi, col, qf, m, l, acc);
            kc_ = kn_; v0c = v0n; v1c = v1n;
            c += 4;
        }
        if (last == qi) chunk_compute<true >(kc_, v0c, v1c, hi, col, qf, m, l, acc);
        else            chunk_compute<false>(kc_, v0c, v1c, hi, col, qf, m, l, acc);
    }
#undef LOADC

    // ---- 4-way merge across key phases ----
    l += __shfl_xor(l, 32, 64);               // combine hi halves per query
    if (lane < 32) { mb[p][col] = m; lb[p][col] = l; }
    __syncthreads();
    float m0 = mb[0][col], m1 = mb[1][col], m2 = mb[2][col], m3 = mb[3][col];
    float M  = fmaxf(fmaxf(m0, m1), fmaxf(m2, m3));
    float L  = lb[0][col]*EXP2F(m0-M) + lb[1][col]*EXP2F(m1-M)
             + lb[2][col]*EXP2F(m2-M) + lb[3][col]*EXP2F(m3-M);
    float fs = EXP2F(m - M);
    float Linv = 1.f / L;
    float fr[16], Lr[16];
    #pragma unroll
    for (int r2 = 0; r2 < 16; ++r2) {
        int row = (r2&3) + 8*(r2>>2) + 4*hi;
        fr[r2] = __shfl(fs,   row, 64);
        Lr[r2] = __shfl(Linv, row, 64);
    }
    if (p > 0 && col < HD) {
        #pragma unroll
        for (int r2 = 0; r2 < 16; ++r2) {
            int row = (r2&3) + 8*(r2>>2) + 4*hi;
            ob[p-1][(row<<3) + col] = acc[r2] * fr[r2];
        }
    }
    __syncthreads();
    if (p == 0 && col < HD) {
        float* og = o + ((size_t)bh*TT + wq0)*HD + col;
        #pragma unroll
        for (int r2 = 0; r2 < 16; ++r2) {
            int row = (r2&3) + 8*(r2>>2) + 4*hi;
            int ix = (row<<3) + col;
            og[(size_t)row * HD] =
                (acc[r2]*fr[r2] + ob[0][ix] + ob[1][ix] + ob[2][ix]) * Lr[r2];
        }
    }
}

// ---------------- Kernel 3: proj + residual + LN2 + FFN (8 threads/row) ----------
__global__ __launch_bounds__(256) void k_proj_ffn(
    const float* __restrict__ h, const float* __restrict__ o,
    const float* __restrict__ Wproj, const float* __restrict__ bproj,
    const float* __restrict__ W1, const float* __restrict__ b1,
    const float* __restrict__ W2, const float* __restrict__ b2,
    const float* __restrict__ g2, const float* __restrict__ bt2,
    float* __restrict__ out)
{
    __shared__ float sWp[DD*36], sW1T[4*DD*36], sW2[4*DD*36];
    __shared__ float sbp[DD], sb1[4*DD], sb2[DD], sg2[DD], sbt2[DD];
    for (int i = threadIdx.x; i < DD*DD; i += 256)      sWp [(i>>5)*36 + (i&31)] = Wproj[i];
    for (int i = threadIdx.x; i < DD*4*DD; i += 256) {
        sW1T[(i&127)*36 + (i>>7)] = W1[i];
        sW2 [(i>>5)*36 + (i&31)]  = W2[i];
    }
    if (threadIdx.x < DD) {
        sbp[threadIdx.x]  = bproj[threadIdx.x];
        sb2[threadIdx.x]  = b2[threadIdx.x];
        sg2[threadIdx.x]  = g2[threadIdx.x];
        sbt2[threadIdx.x] = bt2[threadIdx.x];
    }
    if (threadIdx.x < 4*DD) sb1[threadIdx.x] = b1[threadIdx.x];
    __syncthreads();

    int idx = blockIdx.x * 256 + threadIdx.x;
    int r   = idx >> 3;
    int sub = idx & 7;
    int bb  = r >> 11, tt = r & 2047;

    float o4[4];
    #pragma unroll
    for (int mm = 0; mm < 4; ++mm)
        o4[mm] = o[((size_t)(bb*HH + mm)*TT + tt) * HD + sub];

    float x1[DD];
    #pragma unroll
    for (int d = 0; d < DD; ++d) x1[d] = 0.f;
    #pragma unroll
    for (int mm = 0; mm < 4; ++mm) {
        const float4* wr = (const float4*)&sWp[(sub + 8*mm)*36];
        float ov = o4[mm];
        #pragma unroll
        for (int dc = 0; dc < 8; ++dc) {
            float4 w4 = wr[dc];
            x1[4*dc]   = fmaf(ov, w4.x, x1[4*dc]);
            x1[4*dc+1] = fmaf(ov, w4.y, x1[4*dc+1]);
            x1[4*dc+2] = fmaf(ov, w4.z, x1[4*dc+2]);
            x1[4*dc+3] = fmaf(ov, w4.w, x1[4*dc+3]);
        }
    }
    #pragma unroll
    for (int d = 0; d < DD; ++d) {
        x1[d] += __shfl_xor(x1[d], 1, 64);
        x1[d] += __shfl_xor(x1[d], 2, 64);
        x1[d] += __shfl_xor(x1[d], 4, 64);
    }
    {
        const float4* hp = (const float4*)(h + (size_t)r * DD);
        #pragma unroll
        for (int dc = 0; dc < 8; ++dc) {
            float4 h4 = hp[dc];
            x1[4*dc]   += h4.x + sbp[4*dc];
            x1[4*dc+1] += h4.y + sbp[4*dc+1];
            x1[4*dc+2] += h4.z + sbp[4*dc+2];
            x1[4*dc+3] += h4.w + sbp[4*dc+3];
        }
    }
    float mu = 0.f;
    #pragma unroll
    for (int d = 0; d < DD; ++d) mu += x1[d];
    mu *= (1.f/DD);
    float var = 0.f;
    #pragma unroll
    for (int d = 0; d < DD; ++d) { float dl = x1[d]-mu; var += dl*dl; }
    var *= (1.f/DD);
    float rs = rsqrtf(var + LNEPS);
    float h2v[DD];
    #pragma unroll
    for (int d = 0; d < DD; ++d) h2v[d] = (x1[d]-mu)*rs*sg2[d] + sbt2[d];

    float outp[DD];
    #pragma unroll
    for (int d = 0; d < DD; ++d) outp[d] = 0.f;
    #pragma unroll
    for (int mm = 0; mm < 16; ++mm) {
        int j = sub + 8*mm;
        const float4* w1r = (const float4*)&sW1T[j*36];
        float a = sb1[j];
        #pragma unroll
        for (int dc = 0; dc < 8; ++dc) {
            float4 w4 = w1r[dc];
            a = fmaf(h2v[4*dc], w4.x, a);
            a = fmaf(h2v[4*dc+1], w4.y, a);
            a = fmaf(h2v[4*dc+2], w4.z, a);
            a = fmaf(h2v[4*dc+3], w4.w, a);
        }
        a = fmaxf(a, 0.f);
        const float4* w2r = (const float4*)&sW2[j*36];
        #pragma unroll
        for (int dc = 0; dc < 8; ++dc) {
            float4 w4 = w2r[dc];
            outp[4*dc]   = fmaf(a, w4.x, outp[4*dc]);
            outp[4*dc+1] = fmaf(a, w4.y, outp[4*dc+1]);
            outp[4*dc+2] = fmaf(a, w4.z, outp[4*dc+2]);
            outp[4*dc+3] = fmaf(a, w4.w, outp[4*dc+3]);
        }
    }
    if (sub == 0) {
        #pragma unroll
        for (int d = 0; d < DD; ++d) outp[d] += h2v[d] + sb2[d];
    }
    float t1[16];
    #pragma unroll
    for (int i = 0; i < 16; ++i) {
        bool hib = (sub & 4) != 0;
        float send = hib ? outp[i] : outp[i+16];
        float recv = __shfl_xor(send, 4, 64);
        t1[i] = (hib ? outp[i+16] : outp[i]) + recv;
    }
    float t2[8];
    #pragma unroll
    for (int i = 0; i < 8; ++i) {
        bool hib = (sub & 2) != 0;
        float send = hib ? t1[i] : t1[i+8];
        float recv = __shfl_xor(send, 2, 64);
        t2[i] = (hib ? t1[i+8] : t1[i]) + recv;
    }
    float w0[4];
    #pragma unroll
    for (int i = 0; i < 4; ++i) {
        bool hib = (sub & 1) != 0;
        float send = hib ? t2[i] : t2[i+4];
        float recv = __shfl_xor(send, 1, 64);
        w0[i] = (hib ? t2[i+4] : t2[i]) + recv;
    }
    *(float4*)(out + (size_t)r * DD + sub*4) = make_float4(w0[0], w0[1], w0[2], w0[3]);
}

extern "C" void kernel_launch(void* const* d_in, const int* in_sizes, int n_in,
                              void* d_out, int out_size, void* d_ws, size_t ws_size,
                              hipStream_t stream) {
    const float* x     = (const float*)d_in[0];
    const float* Wq    = (const float*)d_in[1];
    const float* Wk    = (const float*)d_in[2];
    const float* Wv    = (const float*)d_in[3];
    const float* Wproj = (const float*)d_in[4];
    const float* bproj = (const float*)d_in[5];
    const float* ln1_g = (const float*)d_in[6];
    const float* ln1_b = (const float*)d_in[7];
    const float* W1    = (const float*)d_in[8];
    const float* b1    = (const float*)d_in[9];
    const float* W2    = (const float*)d_in[10];
    const float* b2    = (const float*)d_in[11];
    const float* ln2_g = (const float*)d_in[12];
    const float* ln2_b = (const float*)d_in[13];
    float* out = (float*)d_out;

    const size_t N = (size_t)NROWS * DD;   // 524288
    const size_t K = (size_t)BB*HH*TT*4;   // 262144 floats = 1MB per buffer
    float* ws = (float*)d_ws;
    float* h  = ws;                        // N   f32
    float* qh = ws + N;                    // K   f16x8 per row (scaled by 1/sqrt(hd)*log2e)
    float* Kh = ws + N + K;                // K   f16 fragment-major [bh][plane][key][4]
    float* Vt = ws + N + 2*K;              // K   f16 plain V^T [bh][d][t]
    float* o  = ws + N + 3*K;              // N   f32 [bh][t][8]

    k_ln_qkv  <<<512, 256, 0, stream>>>(x, Wq, Wk, Wv, ln1_g, ln1_b, h, qh, Kh, Vt);
    k_attn    <<<2048, 256, 0, stream>>>(qh, Kh, Vt, o);
    k_proj_ffn<<<512, 256, 0, stream>>>(h, o, Wproj, bproj, W1, b1, W2, b2, ln2_g, ln2_b, out);
}

// Round 10
// 125.543 us; speedup vs baseline: 1.0099x; 1.0099x over previous
//
#include <hip/hip_runtime.h>
#include <math.h>

#define BB 8
#define TT 2048
#define DD 32
#define HH 4
#define HD 8
#define NROWS (BB*TT)       // 16384 (B*T); attention rows = B*H*T = 65536
#define LNEPS 1e-5f

#if __has_builtin(__builtin_amdgcn_exp2f)
#define EXP2F(x) __builtin_amdgcn_exp2f(x)
#else
#define EXP2F(x) __expf(0.6931471805599453f*(x))
#endif

typedef _Float16 h2 __attribute__((ext_vector_type(2)));
typedef _Float16 h4v __attribute__((ext_vector_type(4)));
typedef _Float16 h8v __attribute__((ext_vector_type(8)));
typedef float f32x16 __attribute__((ext_vector_type(16)));
struct KH { h2 a, b, c, d; };               // 16B: 8 halves
union F4H { float4 f; KH k; };

static __device__ __forceinline__ h2 pkrtz(float a, float b) {
    return __builtin_bit_cast(h2, __builtin_amdgcn_cvt_pkrtz(a, b));
}
static __device__ __forceinline__ unsigned pkrtz_u(float a, float b) {
    return __builtin_bit_cast(unsigned, __builtin_amdgcn_cvt_pkrtz(a, b));
}
static __device__ __forceinline__ unsigned short f16u(float x) {
    return __builtin_bit_cast(unsigned short, (_Float16)x);
}

#if __has_builtin(__builtin_amdgcn_fdot2)
#define DOT2(a,b,c) __builtin_amdgcn_fdot2((a),(b),(c),false)
#else
#define DOT2(a,b,c) fmaf((float)(a)[1],(float)(b)[1], fmaf((float)(a)[0],(float)(b)[0],(c)))
#endif

// ---------------- Kernel 1: LN1 + QKV projection (8 threads/row) ----------------
__global__ __launch_bounds__(256) void k_ln_qkv(
    const float* __restrict__ x,
    const float* __restrict__ Wq, const float* __restrict__ Wk, const float* __restrict__ Wv,
    const float* __restrict__ g, const float* __restrict__ b,
    float* __restrict__ h, float* __restrict__ qh,
    float* __restrict__ Kh, float* __restrict__ Vt)
{
    __shared__ float sW[3*HH*264];
    __shared__ float sg[DD], sb[DD];
    for (int i = threadIdx.x; i < HH*DD*HD; i += 256) {
        int hd_ = i >> 8, off = i & 255;
        sW[hd_*264 + off]              = Wq[i];
        sW[(4+hd_)*264 + off]          = Wk[i];
        sW[(8+hd_)*264 + off]          = Wv[i];
    }
    if (threadIdx.x < DD) { sg[threadIdx.x] = g[threadIdx.x]; sb[threadIdx.x] = b[threadIdx.x]; }
    __syncthreads();

    int idx = blockIdx.x * 256 + threadIdx.x;     // 0..131071
    int r   = idx >> 3;                           // row 0..16383
    int sub = idx & 7;
    int hh  = sub & 3;
    int dh  = sub >> 2;                           // 0/1 -> dims dh*16..+15
    int bb  = r >> 11, tt = r & 2047;

    float xr[16];
    {
        const float4* xp = (const float4*)(x + (size_t)r * DD + dh*16);
        float4 t0 = xp[0], t1 = xp[1], t2 = xp[2], t3 = xp[3];
        xr[0]=t0.x; xr[1]=t0.y; xr[2]=t0.z; xr[3]=t0.w;
        xr[4]=t1.x; xr[5]=t1.y; xr[6]=t1.z; xr[7]=t1.w;
        xr[8]=t2.x; xr[9]=t2.y; xr[10]=t2.z; xr[11]=t2.w;
        xr[12]=t3.x; xr[13]=t3.y; xr[14]=t3.z; xr[15]=t3.w;
    }
    float s1 = 0.f;
    #pragma unroll
    for (int i = 0; i < 16; ++i) s1 += xr[i];
    s1 += __shfl_xor(s1, 4, 64);
    float mu = s1 * (1.f/DD);
    float sq = 0.f;
    #pragma unroll
    for (int i = 0; i < 16; ++i) { float d = xr[i]-mu; sq += d*d; }
    sq += __shfl_xor(sq, 4, 64);
    float rs = rsqrtf(sq * (1.f/DD) + LNEPS);

    float hr[16];
    #pragma unroll
    for (int i = 0; i < 16; ++i) hr[i] = (xr[i]-mu)*rs*sg[dh*16+i] + sb[dh*16+i];

    {
        float4* hp = (float4*)(h + (size_t)r * DD + dh*16);
        hp[0]=make_float4(hr[0],hr[1],hr[2],hr[3]);
        hp[1]=make_float4(hr[4],hr[5],hr[6],hr[7]);
        hp[2]=make_float4(hr[8],hr[9],hr[10],hr[11]);
        hp[3]=make_float4(hr[12],hr[13],hr[14],hr[15]);
    }

    const float* wq = sW + hh*264 + dh*128;
    const float* wk = sW + (4+hh)*264 + dh*128;
    const float* wv = sW + (8+hh)*264 + dh*128;
    float qa[HD], ka[HD], va[HD];
    #pragma unroll
    for (int k2 = 0; k2 < HD; ++k2) { qa[k2]=0.f; ka[k2]=0.f; va[k2]=0.f; }
    #pragma unroll
    for (int d = 0; d < 16; ++d) {
        float hv = hr[d];
        const float4* wq4 = (const float4*)(wq + d*8);
        const float4* wk4 = (const float4*)(wk + d*8);
        const float4* wv4 = (const float4*)(wv + d*8);
        float4 a0 = wq4[0], a1 = wq4[1];
        float4 b0 = wk4[0], b1 = wk4[1];
        float4 c0 = wv4[0], c1 = wv4[1];
        qa[0]=fmaf(hv,a0.x,qa[0]); qa[1]=fmaf(hv,a0.y,qa[1]); qa[2]=fmaf(hv,a0.z,qa[2]); qa[3]=fmaf(hv,a0.w,qa[3]);
        qa[4]=fmaf(hv,a1.x,qa[4]); qa[5]=fmaf(hv,a1.y,qa[5]); qa[6]=fmaf(hv,a1.z,qa[6]); qa[7]=fmaf(hv,a1.w,qa[7]);
        ka[0]=fmaf(hv,b0.x,ka[0]); ka[1]=fmaf(hv,b0.y,ka[1]); ka[2]=fmaf(hv,b0.z,ka[2]); ka[3]=fmaf(hv,b0.w,ka[3]);
        ka[4]=fmaf(hv,b1.x,ka[4]); ka[5]=fmaf(hv,b1.y,ka[5]); ka[6]=fmaf(hv,b1.z,ka[6]); ka[7]=fmaf(hv,b1.w,ka[7]);
        va[0]=fmaf(hv,c0.x,va[0]); va[1]=fmaf(hv,c0.y,va[1]); va[2]=fmaf(hv,c0.z,va[2]); va[3]=fmaf(hv,c0.w,va[3]);
        va[4]=fmaf(hv,c1.x,va[4]); va[5]=fmaf(hv,c1.y,va[5]); va[6]=fmaf(hv,c1.z,va[6]); va[7]=fmaf(hv,c1.w,va[7]);
    }
    #pragma unroll
    for (int k2 = 0; k2 < HD; ++k2) {
        qa[k2] += __shfl_xor(qa[k2], 4, 64);
        ka[k2] += __shfl_xor(ka[k2], 4, 64);
        va[k2] += __shfl_xor(va[k2], 4, 64);
    }

    const float SCL = 0.35355339059327373f * 1.4426950408889634f;  // 1/sqrt(8)*log2e
    size_t key = (size_t)(bb*HH + hh)*TT + tt;
    unsigned short* vtb = (unsigned short*)Vt + (size_t)(bb*HH + hh)*8*TT + tt;
    if (dh == 0) {
        F4H u;
        u.k.a = pkrtz(qa[0]*SCL, qa[1]*SCL);
        u.k.b = pkrtz(qa[2]*SCL, qa[3]*SCL);
        u.k.c = pkrtz(qa[4]*SCL, qa[5]*SCL);
        u.k.d = pkrtz(qa[6]*SCL, qa[7]*SCL);
        *(float4*)(qh + key*4) = u.f;
        vtb[(size_t)0*TT] = f16u(va[0]);
        vtb[(size_t)1*TT] = f16u(va[1]);
        vtb[(size_t)2*TT] = f16u(va[2]);
        vtb[(size_t)3*TT] = f16u(va[3]);
    } else {
        // K fragment-major: plane0 = halves 0-3, plane1 = halves 4-7
        char* Kb8 = (char*)Kh + (size_t)(bb*HH + hh)*32768;
        uint2 k01; k01.x = pkrtz_u(ka[0],ka[1]); k01.y = pkrtz_u(ka[2],ka[3]);
        uint2 k23; k23.x = pkrtz_u(ka[4],ka[5]); k23.y = pkrtz_u(ka[6],ka[7]);
        *(uint2*)(Kb8 + (size_t)tt*8) = k01;
        *(uint2*)(Kb8 + 16384 + (size_t)tt*8) = k23;
        vtb[(size_t)4*TT] = f16u(va[4]);
        vtb[(size_t)5*TT] = f16u(va[5]);
        vtb[(size_t)6*TT] = f16u(va[6]);
        vtb[(size_t)7*TT] = f16u(va[7]);
    }
}

// ---------------- Kernel 2: 32x32 MFMA flash attention, barrier-free main loop ----
// Wave = 32 queries, 2-way parity-split key range; operands loaded DIRECTLY from L2
// (no LDS staging, no main-loop barriers), software-pipelined 2 chunks ahead.
template<bool DIAG>
__device__ __forceinline__ void chunk_compute(
    uint2 kraw, uint4 v0r, uint4 v1r, int hi, int col,
    h4v qf, float& m, float& l, f32x16& acc)
{
    h4v kf = __builtin_bit_cast(h4v, kraw);
    f32x16 cin;
    #pragma unroll
    for (int r2 = 0; r2 < 16; ++r2) cin[r2] = -m;
    f32x16 S = __builtin_amdgcn_mfma_f32_32x32x8f16(kf, qf, cin, 0, 0, 0);
    if (DIAG) {
        #pragma unroll
        for (int r2 = 0; r2 < 16; ++r2) {
            int row = (r2&3) + 8*(r2>>2) + 4*hi;
            if (row > col) S[r2] = -1e30f;
        }
    }
    float pm = S[0];
    #pragma unroll
    for (int r2 = 1; r2 < 16; ++r2) pm = fmaxf(pm, S[r2]);
    pm = fmaxf(pm, __shfl_xor(pm, 32, 64));
    if (__builtin_expect(__any(pm > 8.f), 0)) {       // defer-max: rare rescale
        float adj = fmaxf(pm, 0.f);
        float cr  = EXP2F(-adj);
        l *= cr;
        #pragma unroll
        for (int r2 = 0; r2 < 16; ++r2) {
            int row = (r2&3) + 8*(r2>>2) + 4*hi;
            acc[r2] *= __shfl(cr, row, 64);
        }
        #pragma unroll
        for (int r2 = 0; r2 < 16; ++r2) S[r2] -= adj;
        m += adj;
    }
    float p[16];
    #pragma unroll
    for (int r2 = 0; r2 < 16; ++r2) p[r2] = EXP2F(S[r2]);
    unsigned pa_ = pkrtz_u(p[0],  p[1]);
    unsigned pb_ = pkrtz_u(p[2],  p[3]);
    unsigned pc_ = pkrtz_u(p[4],  p[5]);
    unsigned pd_ = pkrtz_u(p[6],  p[7]);
    unsigned pe_ = pkrtz_u(p[8],  p[9]);
    unsigned pf_ = pkrtz_u(p[10], p[11]);
    unsigned pg_ = pkrtz_u(p[12], p[13]);
    unsigned ph_ = pkrtz_u(p[14], p[15]);
    const h2 one2 = {(_Float16)1.f, (_Float16)1.f};
    l = DOT2(__builtin_bit_cast(h2, pa_), one2, l);
    l = DOT2(__builtin_bit_cast(h2, pb_), one2, l);
    l = DOT2(__builtin_bit_cast(h2, pc_), one2, l);
    l = DOT2(__builtin_bit_cast(h2, pd_), one2, l);
    l = DOT2(__builtin_bit_cast(h2, pe_), one2, l);
    l = DOT2(__builtin_bit_cast(h2, pf_), one2, l);
    l = DOT2(__builtin_bit_cast(h2, pg_), one2, l);
    l = DOT2(__builtin_bit_cast(h2, ph_), one2, l);
    unsigned ra = (unsigned)__shfl_xor((int)pa_, 32, 64);
    unsigned rb = (unsigned)__shfl_xor((int)pb_, 32, 64);
    unsigned rc = (unsigned)__shfl_xor((int)pc_, 32, 64);
    unsigned rd = (unsigned)__shfl_xor((int)pd_, 32, 64);
    unsigned re = (unsigned)__shfl_xor((int)pe_, 32, 64);
    unsigned rf = (unsigned)__shfl_xor((int)pf_, 32, 64);
    unsigned rg = (unsigned)__shfl_xor((int)pg_, 32, 64);
    unsigned rh = (unsigned)__shfl_xor((int)ph_, 32, 64);
    bool H = (hi != 0);
    uint4 A0 = { H?rc:pa_, H?rd:pb_, H?pc_:ra, H?pd_:rb };   // PV keys +0..15
    uint4 A1 = { H?rg:pe_, H?rh:pf_, H?pg_:re, H?ph_:rf };   // PV keys +16..31
    acc = __builtin_amdgcn_mfma_f32_32x32x16_f16(
        __builtin_bit_cast(h8v, A0), __builtin_bit_cast(h8v, v0r), acc, 0, 0, 0);
    acc = __builtin_amdgcn_mfma_f32_32x32x16_f16(
        __builtin_bit_cast(h8v, A1), __builtin_bit_cast(h8v, v1r), acc, 0, 0, 0);
}

__global__ __launch_bounds__(256) void k_attn(
    const float* __restrict__ qh, const float* __restrict__ Kh,
    const float* __restrict__ Vt, float* __restrict__ o)
{
    __shared__ float mb[128];     // [tl*64 + p*32 + col]
    __shared__ float lb[128];
    __shared__ float ob[512];     // [tl*256 + row*8 + col]
    const int tid  = threadIdx.x;
    const int wave = tid >> 6;
    const int lane = tid & 63;
    const int hi   = lane >> 5;
    const int col  = lane & 31;
    const int tl   = wave >> 1;               // tile slot in block (0/1)
    const int p    = wave & 1;                // key parity
    const int T    = blockIdx.x * 2 + tl;     // global tile id 0..2047
    const int qi   = 63 - (T >> 5);           // q-tile index (heavy first)
    const int bh   = T & 31;
    const int wq0  = qi << 5;

    const char* Kg = (const char*)Kh + (size_t)bh * 32768;   // [plane][2048 keys][8B]
    const char* Vg = (const char*)Vt + (size_t)bh * 32768;   // V^T [8 d][2048 keys]*2B
    const char* Qg = (const char*)qh + (size_t)bh * 32768 + (size_t)wq0 * 16;
    const char* vrow = Vg + (size_t)(col & 7) * 4096;

    // Q B-frag: col = query, k = 4*hi + i
    h4v qf = __builtin_bit_cast(h4v, *(const uint2*)(Qg + col*16 + hi*8));

    f32x16 acc;
    #pragma unroll
    for (int r2 = 0; r2 < 16; ++r2) acc[r2] = 0.f;
    float m = 0.f, l = 0.f;

#define LOADC(c, K2, V0, V1) do { \
    K2 = *(const uint2*)(Kg + hi*16384 + (size_t)((((c)<<5) + col))*8); \
    V0 = *(const uint4*)(vrow + (size_t)((((c)<<5) + (hi<<3)))*2); \
    V1 = *(const uint4*)(vrow + (size_t)((((c)<<5) + 16 + (hi<<3)))*2); \
} while (0)

    const int last = ((qi & 1) == p) ? qi : qi - 1;   // this parity's last chunk
    if (last >= p) {
        // 2-deep software pipeline over chunks c = p, p+2, ..., last
        uint2 k0_, k1_; uint4 v00, v10, v01, v11;
        LOADC(p, k0_, v00, v10);
        const bool two = (p + 2 <= last);
        if (two) LOADC(p + 2, k1_, v01, v11);
        int c = p;
        while (c + 4 <= last) {
            uint2 k2_; uint4 v02, v12;
            LOADC(c + 4, k2_, v02, v12);
            chunk_compute<false>(k0_, v00, v10, hi, col, qf, m, l, acc);
            k0_ = k1_; v00 = v01; v10 = v11;
            k1_ = k2_; v01 = v02; v11 = v12;
            c += 2;
        }
        if (c < last) {     // two chunks remain in registers
            chunk_compute<false>(k0_, v00, v10, hi, col, qf, m, l, acc);
            k0_ = k1_; v00 = v01; v10 = v11;
            c += 2;
        }
        if (last == qi) chunk_compute<true >(k0_, v00, v10, hi, col, qf, m, l, acc);
        else            chunk_compute<false>(k0_, v00, v10, hi, col, qf, m, l, acc);
    }
#undef LOADC

    // ---- merge the two key-parity waves of this tile ----
    l += __shfl_xor(l, 32, 64);               // combine hi halves per query
    if (lane < 32) {
        mb[tl*64 + p*32 + col] = m;
        lb[tl*64 + p*32 + col] = l;
    }
    __syncthreads();
    float mo = mb[tl*64 + (p^1)*32 + col];
    float lo = lb[tl*64 + (p^1)*32 + col];
    float M  = fmaxf(m, mo);
    float fs = EXP2F(m - M);
    float L  = l * fs + lo * EXP2F(mo - M);
    float Linv = 1.f / L;
    float fr[16], Lr[16];
    #pragma unroll
    for (int r2 = 0; r2 < 16; ++r2) {
        int row = (r2&3) + 8*(r2>>2) + 4*hi;
        fr[r2] = __shfl(fs,   row, 64);
        Lr[r2] = __shfl(Linv, row, 64);
    }
    if (p == 1 && col < HD) {
        #pragma unroll
        for (int r2 = 0; r2 < 16; ++r2) {
            int row = (r2&3) + 8*(r2>>2) + 4*hi;
            ob[tl*256 + (row<<3) + col] = acc[r2] * fr[r2];
        }
    }
    __syncthreads();
    if (p == 0 && col < HD) {
        float* og = o + ((size_t)bh*TT + wq0)*HD + col;
        #pragma unroll
        for (int r2 = 0; r2 < 16; ++r2) {
            int row = (r2&3) + 8*(r2>>2) + 4*hi;
            og[(size_t)row * HD] = (acc[r2]*fr[r2] + ob[tl*256 + (row<<3) + col]) * Lr[r2];
        }
    }
}

// ---------------- Kernel 3: proj + residual + LN2 + FFN (8 threads/row) ----------
__global__ __launch_bounds__(256) void k_proj_ffn(
    const float* __restrict__ h, const float* __restrict__ o,
    const float* __restrict__ Wproj, const float* __restrict__ bproj,
    const float* __restrict__ W1, const float* __restrict__ b1,
    const float* __restrict__ W2, const float* __restrict__ b2,
    const float* __restrict__ g2, const float* __restrict__ bt2,
    float* __restrict__ out)
{
    __shared__ float sWp[DD*36], sW1T[4*DD*36], sW2[4*DD*36];
    __shared__ float sbp[DD], sb1[4*DD], sb2[DD], sg2[DD], sbt2[DD];
    for (int i = threadIdx.x; i < DD*DD; i += 256)      sWp [(i>>5)*36 + (i&31)] = Wproj[i];
    for (int i = threadIdx.x; i < DD*4*DD; i += 256) {
        sW1T[(i&127)*36 + (i>>7)] = W1[i];
        sW2 [(i>>5)*36 + (i&31)]  = W2[i];
    }
    if (threadIdx.x < DD) {
        sbp[threadIdx.x]  = bproj[threadIdx.x];
        sb2[threadIdx.x]  = b2[threadIdx.x];
        sg2[threadIdx.x]  = g2[threadIdx.x];
        sbt2[threadIdx.x] = bt2[threadIdx.x];
    }
    if (threadIdx.x < 4*DD) sb1[threadIdx.x] = b1[threadIdx.x];
    __syncthreads();

    int idx = blockIdx.x * 256 + threadIdx.x;
    int r   = idx >> 3;
    int sub = idx & 7;
    int bb  = r >> 11, tt = r & 2047;

    float o4[4];
    #pragma unroll
    for (int mm = 0; mm < 4; ++mm)
        o4[mm] = o[((size_t)(bb*HH + mm)*TT + tt) * HD + sub];

    float x1[DD];
    #pragma unroll
    for (int d = 0; d < DD; ++d) x1[d] = 0.f;
    #pragma unroll
    for (int mm = 0; mm < 4; ++mm) {
        const float4* wr = (const float4*)&sWp[(sub + 8*mm)*36];
        float ov = o4[mm];
        #pragma unroll
        for (int dc = 0; dc < 8; ++dc) {
            float4 w4 = wr[dc];
            x1[4*dc]   = fmaf(ov, w4.x, x1[4*dc]);
            x1[4*dc+1] = fmaf(ov, w4.y, x1[4*dc+1]);
            x1[4*dc+2] = fmaf(ov, w4.z, x1[4*dc+2]);
            x1[4*dc+3] = fmaf(ov, w4.w, x1[4*dc+3]);
        }
    }
    #pragma unroll
    for (int d = 0; d < DD; ++d) {
        x1[d] += __shfl_xor(x1[d], 1, 64);
        x1[d] += __shfl_xor(x1[d], 2, 64);
        x1[d] += __shfl_xor(x1[d], 4, 64);
    }
    {
        const float4* hp = (const float4*)(h + (size_t)r * DD);
        #pragma unroll
        for (int dc = 0; dc < 8; ++dc) {
            float4 h4 = hp[dc];
            x1[4*dc]   += h4.x + sbp[4*dc];
            x1[4*dc+1] += h4.y + sbp[4*dc+1];
            x1[4*dc+2] += h4.z + sbp[4*dc+2];
            x1[4*dc+3] += h4.w + sbp[4*dc+3];
        }
    }
    float mu = 0.f;
    #pragma unroll
    for (int d = 0; d < DD; ++d) mu += x1[d];
    mu *= (1.f/DD);
    float var = 0.f;
    #pragma unroll
    for (int d = 0; d < DD; ++d) { float dl = x1[d]-mu; var += dl*dl; }
    var *= (1.f/DD);
    float rs = rsqrtf(var + LNEPS);
    float h2v[DD];
    #pragma unroll
    for (int d = 0; d < DD; ++d) h2v[d] = (x1[d]-mu)*rs*sg2[d] + sbt2[d];

    float outp[DD];
    #pragma unroll
    for (int d = 0; d < DD; ++d) outp[d] = 0.f;
    #pragma unroll
    for (int mm = 0; mm < 16; ++mm) {
        int j = sub + 8*mm;
        const float4* w1r = (const float4*)&sW1T[j*36];
        float a = sb1[j];
        #pragma unroll
        for (int dc = 0; dc < 8; ++dc) {
            float4 w4 = w1r[dc];
            a = fmaf(h2v[4*dc], w4.x, a);
            a = fmaf(h2v[4*dc+1], w4.y, a);
            a = fmaf(h2v[4*dc+2], w4.z, a);
            a = fmaf(h2v[4*dc+3], w4.w, a);
        }
        a = fmaxf(a, 0.f);
        const float4* w2r = (const float4*)&sW2[j*36];
        #pragma unroll
        for (int dc = 0; dc < 8; ++dc) {
            float4 w4 = w2r[dc];
            outp[4*dc]   = fmaf(a, w4.x, outp[4*dc]);
            outp[4*dc+1] = fmaf(a, w4.y, outp[4*dc+1]);
            outp[4*dc+2] = fmaf(a, w4.z, outp[4*dc+2]);
            outp[4*dc+3] = fmaf(a, w4.w, outp[4*dc+3]);
        }
    }
    if (sub == 0) {
        #pragma unroll
        for (int d = 0; d < DD; ++d) outp[d] += h2v[d] + sb2[d];
    }
    float t1[16];
    #pragma unroll
    for (int i = 0; i < 16; ++i) {
        bool hib = (sub & 4) != 0;
        float send = hib ? outp[i] : outp[i+16];
        float recv = __shfl_xor(send, 4, 64);
        t1[i] = (hib ? outp[i+16] : outp[i]) + recv;
    }
    float t2[8];
    #pragma unroll
    for (int i = 0; i < 8; ++i) {
        bool hib = (sub & 2) != 0;
        float send = hib ? t1[i] : t1[i+8];
        float recv = __shfl_xor(send, 2, 64);
        t2[i] = (hib ? t1[i+8] : t1[i]) + recv;
    }
    float w0[4];
    #pragma unroll
    for (int i = 0; i < 4; ++i) {
        bool hib = (sub & 1) != 0;
        float send = hib ? t2[i] : t2[i+4];
        float recv = __shfl_xor(send, 1, 64);
        w0[i] = (hib ? t2[i+4] : t2[i]) + recv;
    }
    *(float4*)(out + (size_t)r * DD + sub*4) = make_float4(w0[0], w0[1], w0[2], w0[3]);
}

extern "C" void kernel_launch(void* const* d_in, const int* in_sizes, int n_in,
                              void* d_out, int out_size, void* d_ws, size_t ws_size,
                              hipStream_t stream) {
    const float* x     = (const float*)d_in[0];
    const float* Wq    = (const float*)d_in[1];
    const float* Wk    = (const float*)d_in[2];
    const float* Wv    = (const float*)d_in[3];
    const float* Wproj = (const float*)d_in[4];
    const float* bproj = (const float*)d_in[5];
    const float* ln1_g = (const float*)d_in[6];
    const float* ln1_b = (const float*)d_in[7];
    const float* W1    = (const float*)d_in[8];
    const float* b1    = (const float*)d_in[9];
    const float* W2    = (const float*)d_in[10];
    const float* b2    = (const float*)d_in[11];
    const float* ln2_g = (const float*)d_in[12];
    const float* ln2_b = (const float*)d_in[13];
    float* out = (float*)d_out;

    const size_t N = (size_t)NROWS * DD;   // 524288
    const size_t K = (size_t)BB*HH*TT*4;   // 262144 floats = 1MB per buffer
    float* ws = (float*)d_ws;
    float* h  = ws;                        // N   f32
    float* qh = ws + N;                    // K   f16x8 per row (scaled by 1/sqrt(hd)*log2e)
    float* Kh = ws + N + K;                // K   f16 fragment-major [bh][plane][key][4]
    float* Vt = ws + N + 2*K;              // K   f16 plain V^T [bh][d][t]
    float* o  = ws + N + 3*K;              // N   f32 [bh][t][8]

    k_ln_qkv  <<<512, 256, 0, stream>>>(x, Wq, Wk, Wv, ln1_g, ln1_b, h, qh, Kh, Vt);
    k_attn    <<<1024, 256, 0, stream>>>(qh, Kh, Vt, o);
    k_proj_ffn<<<512, 256, 0, stream>>>(h, o, Wproj, bproj, W1, b1, W2, b2, ln2_g, ln2_b, out);
}

// Round 11
// 122.979 us; speedup vs baseline: 1.0310x; 1.0208x over previous
//
#include <hip/hip_runtime.h>
#include <math.h>

#define BB 8
#define TT 2048
#define DD 32
#define HH 4
#define HD 8
#define NROWS (BB*TT)       // 16384 (B*T); attention rows = B*H*T = 65536
#define LNEPS 1e-5f

#if __has_builtin(__builtin_amdgcn_exp2f)
#define EXP2F(x) __builtin_amdgcn_exp2f(x)
#else
#define EXP2F(x) __expf(0.6931471805599453f*(x))
#endif

typedef _Float16 h2 __attribute__((ext_vector_type(2)));
typedef _Float16 h4v __attribute__((ext_vector_type(4)));
typedef _Float16 h8v __attribute__((ext_vector_type(8)));
typedef float f32x16 __attribute__((ext_vector_type(16)));
struct KH { h2 a, b, c, d; };               // 16B: 8 halves
union F4H { float4 f; KH k; };

static __device__ __forceinline__ h2 pkrtz(float a, float b) {
    return __builtin_bit_cast(h2, __builtin_amdgcn_cvt_pkrtz(a, b));
}
static __device__ __forceinline__ unsigned pkrtz_u(float a, float b) {
    return __builtin_bit_cast(unsigned, __builtin_amdgcn_cvt_pkrtz(a, b));
}
static __device__ __forceinline__ unsigned short f16u(float x) {
    return __builtin_bit_cast(unsigned short, (_Float16)x);
}

#if __has_builtin(__builtin_amdgcn_fdot2)
#define DOT2(a,b,c) __builtin_amdgcn_fdot2((a),(b),(c),false)
#else
#define DOT2(a,b,c) fmaf((float)(a)[1],(float)(b)[1], fmaf((float)(a)[0],(float)(b)[0],(c)))
#endif

// ---------------- Kernel 1: LN1 + QKV projection (8 threads/row) ----------------
__global__ __launch_bounds__(256) void k_ln_qkv(
    const float* __restrict__ x,
    const float* __restrict__ Wq, const float* __restrict__ Wk, const float* __restrict__ Wv,
    const float* __restrict__ g, const float* __restrict__ b,
    float* __restrict__ h, float* __restrict__ qh,
    float* __restrict__ Kh, float* __restrict__ Vt)
{
    __shared__ float sW[3*HH*264];
    __shared__ float sg[DD], sb[DD];
    for (int i = threadIdx.x; i < HH*DD*HD; i += 256) {
        int hd_ = i >> 8, off = i & 255;
        sW[hd_*264 + off]              = Wq[i];
        sW[(4+hd_)*264 + off]          = Wk[i];
        sW[(8+hd_)*264 + off]          = Wv[i];
    }
    if (threadIdx.x < DD) { sg[threadIdx.x] = g[threadIdx.x]; sb[threadIdx.x] = b[threadIdx.x]; }
    __syncthreads();

    int idx = blockIdx.x * 256 + threadIdx.x;     // 0..131071
    int r   = idx >> 3;                           // row 0..16383
    int sub = idx & 7;
    int hh  = sub & 3;
    int dh  = sub >> 2;                           // 0/1 -> dims dh*16..+15
    int bb  = r >> 11, tt = r & 2047;

    float xr[16];
    {
        const float4* xp = (const float4*)(x + (size_t)r * DD + dh*16);
        float4 t0 = xp[0], t1 = xp[1], t2 = xp[2], t3 = xp[3];
        xr[0]=t0.x; xr[1]=t0.y; xr[2]=t0.z; xr[3]=t0.w;
        xr[4]=t1.x; xr[5]=t1.y; xr[6]=t1.z; xr[7]=t1.w;
        xr[8]=t2.x; xr[9]=t2.y; xr[10]=t2.z; xr[11]=t2.w;
        xr[12]=t3.x; xr[13]=t3.y; xr[14]=t3.z; xr[15]=t3.w;
    }
    float s1 = 0.f;
    #pragma unroll
    for (int i = 0; i < 16; ++i) s1 += xr[i];
    s1 += __shfl_xor(s1, 4, 64);
    float mu = s1 * (1.f/DD);
    float sq = 0.f;
    #pragma unroll
    for (int i = 0; i < 16; ++i) { float d = xr[i]-mu; sq += d*d; }
    sq += __shfl_xor(sq, 4, 64);
    float rs = rsqrtf(sq * (1.f/DD) + LNEPS);

    float hr[16];
    #pragma unroll
    for (int i = 0; i < 16; ++i) hr[i] = (xr[i]-mu)*rs*sg[dh*16+i] + sb[dh*16+i];

    {
        float4* hp = (float4*)(h + (size_t)r * DD + dh*16);
        hp[0]=make_float4(hr[0],hr[1],hr[2],hr[3]);
        hp[1]=make_float4(hr[4],hr[5],hr[6],hr[7]);
        hp[2]=make_float4(hr[8],hr[9],hr[10],hr[11]);
        hp[3]=make_float4(hr[12],hr[13],hr[14],hr[15]);
    }

    const float* wq = sW + hh*264 + dh*128;
    const float* wk = sW + (4+hh)*264 + dh*128;
    const float* wv = sW + (8+hh)*264 + dh*128;
    float qa[HD], ka[HD], va[HD];
    #pragma unroll
    for (int k2 = 0; k2 < HD; ++k2) { qa[k2]=0.f; ka[k2]=0.f; va[k2]=0.f; }
    #pragma unroll
    for (int d = 0; d < 16; ++d) {
        float hv = hr[d];
        const float4* wq4 = (const float4*)(wq + d*8);
        const float4* wk4 = (const float4*)(wk + d*8);
        const float4* wv4 = (const float4*)(wv + d*8);
        float4 a0 = wq4[0], a1 = wq4[1];
        float4 b0 = wk4[0], b1 = wk4[1];
        float4 c0 = wv4[0], c1 = wv4[1];
        qa[0]=fmaf(hv,a0.x,qa[0]); qa[1]=fmaf(hv,a0.y,qa[1]); qa[2]=fmaf(hv,a0.z,qa[2]); qa[3]=fmaf(hv,a0.w,qa[3]);
        qa[4]=fmaf(hv,a1.x,qa[4]); qa[5]=fmaf(hv,a1.y,qa[5]); qa[6]=fmaf(hv,a1.z,qa[6]); qa[7]=fmaf(hv,a1.w,qa[7]);
        ka[0]=fmaf(hv,b0.x,ka[0]); ka[1]=fmaf(hv,b0.y,ka[1]); ka[2]=fmaf(hv,b0.z,ka[2]); ka[3]=fmaf(hv,b0.w,ka[3]);
        ka[4]=fmaf(hv,b1.x,ka[4]); ka[5]=fmaf(hv,b1.y,ka[5]); ka[6]=fmaf(hv,b1.z,ka[6]); ka[7]=fmaf(hv,b1.w,ka[7]);
        va[0]=fmaf(hv,c0.x,va[0]); va[1]=fmaf(hv,c0.y,va[1]); va[2]=fmaf(hv,c0.z,va[2]); va[3]=fmaf(hv,c0.w,va[3]);
        va[4]=fmaf(hv,c1.x,va[4]); va[5]=fmaf(hv,c1.y,va[5]); va[6]=fmaf(hv,c1.z,va[6]); va[7]=fmaf(hv,c1.w,va[7]);
    }
    #pragma unroll
    for (int k2 = 0; k2 < HD; ++k2) {
        qa[k2] += __shfl_xor(qa[k2], 4, 64);
        ka[k2] += __shfl_xor(ka[k2], 4, 64);
        va[k2] += __shfl_xor(va[k2], 4, 64);
    }

    const float SCL = 0.35355339059327373f * 1.4426950408889634f;  // 1/sqrt(8)*log2e
    size_t key = (size_t)(bb*HH + hh)*TT + tt;
    unsigned short* vtb = (unsigned short*)Vt + (size_t)(bb*HH + hh)*8*TT + tt;
    if (dh == 0) {
        F4H u;
        u.k.a = pkrtz(qa[0]*SCL, qa[1]*SCL);
        u.k.b = pkrtz(qa[2]*SCL, qa[3]*SCL);
        u.k.c = pkrtz(qa[4]*SCL, qa[5]*SCL);
        u.k.d = pkrtz(qa[6]*SCL, qa[7]*SCL);
        *(float4*)(qh + key*4) = u.f;
        vtb[(size_t)0*TT] = f16u(va[0]);
        vtb[(size_t)1*TT] = f16u(va[1]);
        vtb[(size_t)2*TT] = f16u(va[2]);
        vtb[(size_t)3*TT] = f16u(va[3]);
    } else {
        // K fragment-major: plane0 = halves 0-3, plane1 = halves 4-7
        char* Kb8 = (char*)Kh + (size_t)(bb*HH + hh)*32768;
        uint2 k01; k01.x = pkrtz_u(ka[0],ka[1]); k01.y = pkrtz_u(ka[2],ka[3]);
        uint2 k23; k23.x = pkrtz_u(ka[4],ka[5]); k23.y = pkrtz_u(ka[6],ka[7]);
        *(uint2*)(Kb8 + (size_t)tt*8) = k01;
        *(uint2*)(Kb8 + 16384 + (size_t)tt*8) = k23;
        vtb[(size_t)4*TT] = f16u(va[4]);
        vtb[(size_t)5*TT] = f16u(va[5]);
        vtb[(size_t)6*TT] = f16u(va[6]);
        vtb[(size_t)7*TT] = f16u(va[7]);
    }
}

// ---------------- Kernel 2: 32x32 MFMA flash attention, barrier-free main loop ----
// Wave = 32 queries, parity-split key range; operands loaded DIRECTLY from L2
// (no LDS staging, no main-loop barriers), software-pipelined 1 chunk ahead.
// MEASURED BEST (123.1 us total): 2-way split / 1-deep pipeline; 4-way split and
// 2-deep pipeline both regressed (126.8 / 125.5).
template<bool DIAG>
__device__ __forceinline__ void chunk_compute(
    uint2 kraw, uint4 v0r, uint4 v1r, int hi, int col,
    h4v qf, float& m, float& l, f32x16& acc)
{
    h4v kf = __builtin_bit_cast(h4v, kraw);
    f32x16 cin;
    #pragma unroll
    for (int r2 = 0; r2 < 16; ++r2) cin[r2] = -m;
    f32x16 S = __builtin_amdgcn_mfma_f32_32x32x8f16(kf, qf, cin, 0, 0, 0);
    if (DIAG) {
        #pragma unroll
        for (int r2 = 0; r2 < 16; ++r2) {
            int row = (r2&3) + 8*(r2>>2) + 4*hi;
            if (row > col) S[r2] = -1e30f;
        }
    }
    float pm = S[0];
    #pragma unroll
    for (int r2 = 1; r2 < 16; ++r2) pm = fmaxf(pm, S[r2]);
    pm = fmaxf(pm, __shfl_xor(pm, 32, 64));
    if (__builtin_expect(__any(pm > 8.f), 0)) {       // defer-max: rare rescale
        float adj = fmaxf(pm, 0.f);
        float cr  = EXP2F(-adj);
        l *= cr;
        #pragma unroll
        for (int r2 = 0; r2 < 16; ++r2) {
            int row = (r2&3) + 8*(r2>>2) + 4*hi;
            acc[r2] *= __shfl(cr, row, 64);
        }
        #pragma unroll
        for (int r2 = 0; r2 < 16; ++r2) S[r2] -= adj;
        m += adj;
    }
    float p[16];
    #pragma unroll
    for (int r2 = 0; r2 < 16; ++r2) p[r2] = EXP2F(S[r2]);
    unsigned pa_ = pkrtz_u(p[0],  p[1]);
    unsigned pb_ = pkrtz_u(p[2],  p[3]);
    unsigned pc_ = pkrtz_u(p[4],  p[5]);
    unsigned pd_ = pkrtz_u(p[6],  p[7]);
    unsigned pe_ = pkrtz_u(p[8],  p[9]);
    unsigned pf_ = pkrtz_u(p[10], p[11]);
    unsigned pg_ = pkrtz_u(p[12], p[13]);
    unsigned ph_ = pkrtz_u(p[14], p[15]);
    const h2 one2 = {(_Float16)1.f, (_Float16)1.f};
    l = DOT2(__builtin_bit_cast(h2, pa_), one2, l);
    l = DOT2(__builtin_bit_cast(h2, pb_), one2, l);
    l = DOT2(__builtin_bit_cast(h2, pc_), one2, l);
    l = DOT2(__builtin_bit_cast(h2, pd_), one2, l);
    l = DOT2(__builtin_bit_cast(h2, pe_), one2, l);
    l = DOT2(__builtin_bit_cast(h2, pf_), one2, l);
    l = DOT2(__builtin_bit_cast(h2, pg_), one2, l);
    l = DOT2(__builtin_bit_cast(h2, ph_), one2, l);
    unsigned ra = (unsigned)__shfl_xor((int)pa_, 32, 64);
    unsigned rb = (unsigned)__shfl_xor((int)pb_, 32, 64);
    unsigned rc = (unsigned)__shfl_xor((int)pc_, 32, 64);
    unsigned rd = (unsigned)__shfl_xor((int)pd_, 32, 64);
    unsigned re = (unsigned)__shfl_xor((int)pe_, 32, 64);
    unsigned rf = (unsigned)__shfl_xor((int)pf_, 32, 64);
    unsigned rg = (unsigned)__shfl_xor((int)pg_, 32, 64);
    unsigned rh = (unsigned)__shfl_xor((int)ph_, 32, 64);
    bool H = (hi != 0);
    uint4 A0 = { H?rc:pa_, H?rd:pb_, H?pc_:ra, H?pd_:rb };   // PV keys +0..15
    uint4 A1 = { H?rg:pe_, H?rh:pf_, H?pg_:re, H?ph_:rf };   // PV keys +16..31
    acc = __builtin_amdgcn_mfma_f32_32x32x16_f16(
        __builtin_bit_cast(h8v, A0), __builtin_bit_cast(h8v, v0r), acc, 0, 0, 0);
    acc = __builtin_amdgcn_mfma_f32_32x32x16_f16(
        __builtin_bit_cast(h8v, A1), __builtin_bit_cast(h8v, v1r), acc, 0, 0, 0);
}

__global__ __launch_bounds__(256) void k_attn(
    const float* __restrict__ qh, const float* __restrict__ Kh,
    const float* __restrict__ Vt, float* __restrict__ o)
{
    __shared__ float mb[128];     // [tl*64 + p*32 + col]
    __shared__ float lb[128];
    __shared__ float ob[512];     // [tl*256 + row*8 + col]
    const int tid  = threadIdx.x;
    const int wave = tid >> 6;
    const int lane = tid & 63;
    const int hi   = lane >> 5;
    const int col  = lane & 31;
    const int tl   = wave >> 1;               // tile slot in block (0/1)
    const int p    = wave & 1;                // key parity
    const int T    = blockIdx.x * 2 + tl;     // global tile id 0..2047
    const int qi   = 63 - (T >> 5);           // q-tile index (heavy first)
    const int bh   = T & 31;
    const int wq0  = qi << 5;

    const char* Kg = (const char*)Kh + (size_t)bh * 32768;   // [plane][2048 keys][8B]
    const char* Vg = (const char*)Vt + (size_t)bh * 32768;   // V^T [8 d][2048 keys]*2B
    const char* Qg = (const char*)qh + (size_t)bh * 32768 + (size_t)wq0 * 16;
    const char* vrow = Vg + (size_t)(col & 7) * 4096;

    // Q B-frag: col = query, k = 4*hi + i
    h4v qf = __builtin_bit_cast(h4v, *(const uint2*)(Qg + col*16 + hi*8));

    f32x16 acc;
    #pragma unroll
    for (int r2 = 0; r2 < 16; ++r2) acc[r2] = 0.f;
    float m = 0.f, l = 0.f;

#define LOADC(c, K2, V0, V1) do { \
    K2 = *(const uint2*)(Kg + hi*16384 + (size_t)((((c)<<5) + col))*8); \
    V0 = *(const uint4*)(vrow + (size_t)((((c)<<5) + (hi<<3)))*2); \
    V1 = *(const uint4*)(vrow + (size_t)((((c)<<5) + 16 + (hi<<3)))*2); \
} while (0)

    const int last = ((qi & 1) == p) ? qi : qi - 1;   // this parity's last chunk
    if (last >= p) {
        uint2 kc_; uint4 v0c, v1c;
        LOADC(p, kc_, v0c, v1c);
        int c = p;
        while (c < last) {
            uint2 kn_; uint4 v0n, v1n;
            LOADC(c + 2, kn_, v0n, v1n);
            chunk_compute<false>(kc_, v0c, v1c, hi, col, qf, m, l, acc);
            kc_ = kn_; v0c = v0n; v1c = v1n;
            c += 2;
        }
        if (last == qi) chunk_compute<true >(kc_, v0c, v1c, hi, col, qf, m, l, acc);
        else            chunk_compute<false>(kc_, v0c, v1c, hi, col, qf, m, l, acc);
    }
#undef LOADC

    // ---- merge the two key-parity waves of this tile ----
    l += __shfl_xor(l, 32, 64);               // combine hi halves per query
    if (lane < 32) {
        mb[tl*64 + p*32 + col] = m;
        lb[tl*64 + p*32 + col] = l;
    }
    __syncthreads();
    float mo = mb[tl*64 + (p^1)*32 + col];
    float lo = lb[tl*64 + (p^1)*32 + col];
    float M  = fmaxf(m, mo);
    float fs = EXP2F(m - M);
    float L  = l * fs + lo * EXP2F(mo - M);
    float Linv = 1.f / L;
    float fr[16], Lr[16];
    #pragma unroll
    for (int r2 = 0; r2 < 16; ++r2) {
        int row = (r2&3) + 8*(r2>>2) + 4*hi;
        fr[r2] = __shfl(fs,   row, 64);
        Lr[r2] = __shfl(Linv, row, 64);
    }
    if (p == 1 && col < HD) {
        #pragma unroll
        for (int r2 = 0; r2 < 16; ++r2) {
            int row = (r2&3) + 8*(r2>>2) + 4*hi;
            ob[tl*256 + (row<<3) + col] = acc[r2] * fr[r2];
        }
    }
    __syncthreads();
    if (p == 0 && col < HD) {
        float* og = o + ((size_t)bh*TT + wq0)*HD + col;
        #pragma unroll
        for (int r2 = 0; r2 < 16; ++r2) {
            int row = (r2&3) + 8*(r2>>2) + 4*hi;
            og[(size_t)row * HD] = (acc[r2]*fr[r2] + ob[tl*256 + (row<<3) + col]) * Lr[r2];
        }
    }
}

// ---------------- Kernel 3: proj + residual + LN2 + FFN (8 threads/row) ----------
__global__ __launch_bounds__(256) void k_proj_ffn(
    const float* __restrict__ h, const float* __restrict__ o,
    const float* __restrict__ Wproj, const float* __restrict__ bproj,
    const float* __restrict__ W1, const float* __restrict__ b1,
    const float* __restrict__ W2, const float* __restrict__ b2,
    const float* __restrict__ g2, const float* __restrict__ bt2,
    float* __restrict__ out)
{
    __shared__ float sWp[DD*36], sW1T[4*DD*36], sW2[4*DD*36];
    __shared__ float sbp[DD], sb1[4*DD], sb2[DD], sg2[DD], sbt2[DD];
    for (int i = threadIdx.x; i < DD*DD; i += 256)      sWp [(i>>5)*36 + (i&31)] = Wproj[i];
    for (int i = threadIdx.x; i < DD*4*DD; i += 256) {
        sW1T[(i&127)*36 + (i>>7)] = W1[i];
        sW2 [(i>>5)*36 + (i&31)]  = W2[i];
    }
    if (threadIdx.x < DD) {
        sbp[threadIdx.x]  = bproj[threadIdx.x];
        sb2[threadIdx.x]  = b2[threadIdx.x];
        sg2[threadIdx.x]  = g2[threadIdx.x];
        sbt2[threadIdx.x] = bt2[threadIdx.x];
    }
    if (threadIdx.x < 4*DD) sb1[threadIdx.x] = b1[threadIdx.x];
    __syncthreads();

    int idx = blockIdx.x * 256 + threadIdx.x;
    int r   = idx >> 3;
    int sub = idx & 7;
    int bb  = r >> 11, tt = r & 2047;

    float o4[4];
    #pragma unroll
    for (int mm = 0; mm < 4; ++mm)
        o4[mm] = o[((size_t)(bb*HH + mm)*TT + tt) * HD + sub];

    float x1[DD];
    #pragma unroll
    for (int d = 0; d < DD; ++d) x1[d] = 0.f;
    #pragma unroll
    for (int mm = 0; mm < 4; ++mm) {
        const float4* wr = (const float4*)&sWp[(sub + 8*mm)*36];
        float ov = o4[mm];
        #pragma unroll
        for (int dc = 0; dc < 8; ++dc) {
            float4 w4 = wr[dc];
            x1[4*dc]   = fmaf(ov, w4.x, x1[4*dc]);
            x1[4*dc+1] = fmaf(ov, w4.y, x1[4*dc+1]);
            x1[4*dc+2] = fmaf(ov, w4.z, x1[4*dc+2]);
            x1[4*dc+3] = fmaf(ov, w4.w, x1[4*dc+3]);
        }
    }
    #pragma unroll
    for (int d = 0; d < DD; ++d) {
        x1[d] += __shfl_xor(x1[d], 1, 64);
        x1[d] += __shfl_xor(x1[d], 2, 64);
        x1[d] += __shfl_xor(x1[d], 4, 64);
    }
    {
        const float4* hp = (const float4*)(h + (size_t)r * DD);
        #pragma unroll
        for (int dc = 0; dc < 8; ++dc) {
            float4 h4 = hp[dc];
            x1[4*dc]   += h4.x + sbp[4*dc];
            x1[4*dc+1] += h4.y + sbp[4*dc+1];
            x1[4*dc+2] += h4.z + sbp[4*dc+2];
            x1[4*dc+3] += h4.w + sbp[4*dc+3];
        }
    }
    float mu = 0.f;
    #pragma unroll
    for (int d = 0; d < DD; ++d) mu += x1[d];
    mu *= (1.f/DD);
    float var = 0.f;
    #pragma unroll
    for (int d = 0; d < DD; ++d) { float dl = x1[d]-mu; var += dl*dl; }
    var *= (1.f/DD);
    float rs = rsqrtf(var + LNEPS);
    float h2v[DD];
    #pragma unroll
    for (int d = 0; d < DD; ++d) h2v[d] = (x1[d]-mu)*rs*sg2[d] + sbt2[d];

    float outp[DD];
    #pragma unroll
    for (int d = 0; d < DD; ++d) outp[d] = 0.f;
    #pragma unroll
    for (int mm = 0; mm < 16; ++mm) {
        int j = sub + 8*mm;
        const float4* w1r = (const float4*)&sW1T[j*36];
        float a = sb1[j];
        #pragma unroll
        for (int dc = 0; dc < 8; ++dc) {
            float4 w4 = w1r[dc];
            a = fmaf(h2v[4*dc], w4.x, a);
            a = fmaf(h2v[4*dc+1], w4.y, a);
            a = fmaf(h2v[4*dc+2], w4.z, a);
            a = fmaf(h2v[4*dc+3], w4.w, a);
        }
        a = fmaxf(a, 0.f);
        const float4* w2r = (const float4*)&sW2[j*36];
        #pragma unroll
        for (int dc = 0; dc < 8; ++dc) {
            float4 w4 = w2r[dc];
            outp[4*dc]   = fmaf(a, w4.x, outp[4*dc]);
            outp[4*dc+1] = fmaf(a, w4.y, outp[4*dc+1]);
            outp[4*dc+2] = fmaf(a, w4.z, outp[4*dc+2]);
            outp[4*dc+3] = fmaf(a, w4.w, outp[4*dc+3]);
        }
    }
    if (sub == 0) {
        #pragma unroll
        for (int d = 0; d < DD; ++d) outp[d] += h2v[d] + sb2[d];
    }
    float t1[16];
    #pragma unroll
    for (int i = 0; i < 16; ++i) {
        bool hib = (sub & 4) != 0;
        float send = hib ? outp[i] : outp[i+16];
        float recv = __shfl_xor(send, 4, 64);
        t1[i] = (hib ? outp[i+16] : outp[i]) + recv;
    }
    float t2[8];
    #pragma unroll
    for (int i = 0; i < 8; ++i) {
        bool hib = (sub & 2) != 0;
        float send = hib ? t1[i] : t1[i+8];
        float recv = __shfl_xor(send, 2, 64);
        t2[i] = (hib ? t1[i+8] : t1[i]) + recv;
    }
    float w0[4];
    #pragma unroll
    for (int i = 0; i < 4; ++i) {
        bool hib = (sub & 1) != 0;
        float send = hib ? t2[i] : t2[i+4];
        float recv = __shfl_xor(send, 1, 64);
        w0[i] = (hib ? t2[i+4] : t2[i]) + recv;
    }
    *(float4*)(out + (size_t)r * DD + sub*4) = make_float4(w0[0], w0[1], w0[2], w0[3]);
}

extern "C" void kernel_launch(void* const* d_in, const int* in_sizes, int n_in,
                              void* d_out, int out_size, void* d_ws, size_t ws_size,
                              hipStream_t stream) {
    const float* x     = (const float*)d_in[0];
    const float* Wq    = (const float*)d_in[1];
    const float* Wk    = (const float*)d_in[2];
    const float* Wv    = (const float*)d_in[3];
    const float* Wproj = (const float*)d_in[4];
    const float* bproj = (const float*)d_in[5];
    const float* ln1_g = (const float*)d_in[6];
    const float* ln1_b = (const float*)d_in[7];
    const float* W1    = (const float*)d_in[8];
    const float* b1    = (const float*)d_in[9];
    const float* W2    = (const float*)d_in[10];
    const float* b2    = (const float*)d_in[11];
    const float* ln2_g = (const float*)d_in[12];
    const float* ln2_b = (const float*)d_in[13];
    float* out = (float*)d_out;

    const size_t N = (size_t)NROWS * DD;   // 524288
    const size_t K = (size_t)BB*HH*TT*4;   // 262144 floats = 1MB per buffer
    float* ws = (float*)d_ws;
    float* h  = ws;                        // N   f32
    float* qh = ws + N;                    // K   f16x8 per row (scaled by 1/sqrt(hd)*log2e)
    float* Kh = ws + N + K;                // K   f16 fragment-major [bh][plane][key][4]
    float* Vt = ws + N + 2*K;              // K   f16 plain V^T [bh][d][t]
    float* o  = ws + N + 3*K;              // N   f32 [bh][t][8]

    k_ln_qkv  <<<512, 256, 0, stream>>>(x, Wq, Wk, Wv, ln1_g, ln1_b, h, qh, Kh, Vt);
    k_attn    <<<1024, 256, 0, stream>>>(qh, Kh, Vt, o);
    k_proj_ffn<<<512, 256, 0, stream>>>(h, o, Wproj, bproj, W1, b1, W2, b2, ln2_g, ln2_b, out);
}